// Round 8
// baseline (220.476 us; speedup 1.0000x reference)
//
#include <hip/hip_runtime.h>
#include <hip/hip_bf16.h>

// Problem constants (fixed by the reference: B=4,S=2048,D=1024,E=8,H=1024)
#define T_TOK 8192
#define DDIM  1024
#define NEXP  8
#define HDIM  1024
#define SLOT_CAP 17536   // 137 M-tiles * 128; >= 16384 + 8*127 padding worst case
#define NCBLK 32         // blocks for count/slotfill

typedef short bf16x8 __attribute__((ext_vector_type(8)));   // 8 bf16 in 4 VGPRs
typedef float f32x4  __attribute__((ext_vector_type(4)));

typedef const __attribute__((address_space(1))) unsigned int* gas_ptr;
typedef __attribute__((address_space(3))) unsigned int*       las_ptr;
#define GLD16(gp, lp) __builtin_amdgcn_global_load_lds((gas_ptr)(gp), (las_ptr)(lp), 16, 0, 0)

// fp32 -> bf16 round-to-nearest-even
static __device__ __forceinline__ unsigned short f2b(float f) {
    union { float f; unsigned int u; } v; v.f = f;
    unsigned int u = v.u;
    u += 0x7fffu + ((u >> 16) & 1u);
    return (unsigned short)(u >> 16);
}
static __device__ __forceinline__ float b2f(unsigned short h) {
    union { unsigned int u; float f; } v; v.u = ((unsigned int)h) << 16;
    return v.f;
}

// ---------------------------------------------------------------------------
// K1: routing. One block per token: fp64 logits (selection-exact vs numpy),
// softmax top-2 renormalized, 2-stage LDS reduction. Fused x -> bf16.
// R7 fix: Wg loads were 32 scalar dwords/thread (67M load instrs kernel-wide,
// the hidden aux cost). Now 8x float4 — same values, same fp64 accumulation
// ORDER (bit-identical selection).
// ---------------------------------------------------------------------------
__global__ __launch_bounds__(256) void moe_routing(
    const float* __restrict__ x, const float* __restrict__ wg,
    unsigned short* __restrict__ xb,
    int* __restrict__ tok_e, float* __restrict__ tok_g)
{
    __shared__ double red[256 * 9];   // [thread][expert], stride 9 (bank spread)
    __shared__ double part[64];
    __shared__ double lf[NEXP];

    int t   = blockIdx.x;
    int tid = threadIdx.x;

    float4 xv = ((const float4*)(x + (size_t)t * DDIM))[tid];
    ushort4 xs;
    xs.x = f2b(xv.x); xs.y = f2b(xv.y); xs.z = f2b(xv.z); xs.w = f2b(xv.w);
    ((ushort4*)(xb + (size_t)t * DDIM))[tid] = xs;

    double s[NEXP];
    #pragma unroll
    for (int e = 0; e < NEXP; e++) s[e] = 0.0;
    const float4* wr4 = (const float4*)(wg + (size_t)tid * 4 * NEXP);
    #pragma unroll
    for (int j = 0; j < 4; j++) {
        double xj = (double)((&xv.x)[j]);
        float4 qa = wr4[2 * j];        // row 4*tid+j, experts 0..3
        float4 qb = wr4[2 * j + 1];    // row 4*tid+j, experts 4..7
        s[0] += xj * (double)qa.x;
        s[1] += xj * (double)qa.y;
        s[2] += xj * (double)qa.z;
        s[3] += xj * (double)qa.w;
        s[4] += xj * (double)qb.x;
        s[5] += xj * (double)qb.y;
        s[6] += xj * (double)qb.z;
        s[7] += xj * (double)qb.w;
    }
    #pragma unroll
    for (int e = 0; e < NEXP; e++) red[tid * 9 + e] = s[e];
    __syncthreads();

    if (tid < 64) {
        int e = tid >> 3, p = tid & 7;
        double acc = 0.0;
        for (int i = 0; i < 32; i++) acc += red[(i * 8 + p) * 9 + e];
        part[tid] = acc;
    }
    __syncthreads();
    if (tid < NEXP) {
        double acc = 0.0;
        #pragma unroll
        for (int p = 0; p < 8; p++) acc += part[tid * 8 + p];
        lf[tid] = acc;
    }
    __syncthreads();

    if (tid == 0) {
        double l[NEXP];
        #pragma unroll
        for (int e = 0; e < NEXP; e++) l[e] = lf[e];
        int e0 = 0;
        for (int e = 1; e < NEXP; e++) if (l[e] > l[e0]) e0 = e;
        int e1 = (e0 == 0) ? 1 : 0;
        for (int e = 0; e < NEXP; e++) if (e != e0 && l[e] > l[e1]) e1 = e;
        double g0 = 1.0 / (1.0 + exp(l[e1] - l[e0]));
        double g1 = 1.0 - g0;
        tok_e[2*t] = e0; tok_e[2*t+1] = e1;
        tok_g[2*t] = (float)g0; tok_g[2*t+1] = (float)g1;
    }
}

// K2a: per-block expert histogram -> cnt_part[b][e].
__global__ __launch_bounds__(256) void moe_count(
    const int* __restrict__ tok_e, int* __restrict__ cnt_part)
{
    __shared__ int h[NEXP];
    if (threadIdx.x < NEXP) h[threadIdx.x] = 0;
    __syncthreads();
    int t = blockIdx.x * 256 + threadIdx.x;
    atomicAdd(&h[tok_e[2*t]], 1);
    atomicAdd(&h[tok_e[2*t+1]], 1);
    __syncthreads();
    if (threadIdx.x < NEXP)
        cnt_part[blockIdx.x * NEXP + threadIdx.x] = h[threadIdx.x];
}

// K2b: reduce partials, 128-aligned prefix, init cursors. 1 block.
__global__ void moe_offsets(const int* __restrict__ cnt_part,
                            int* __restrict__ meta, int* __restrict__ counts,
                            int* __restrict__ cursor) {
    __shared__ int c_s[NEXP];
    int tid = threadIdx.x;
    if (tid < NEXP) {
        int c = 0;
        for (int b = 0; b < NCBLK; b++) c += cnt_part[b * NEXP + tid];
        counts[tid] = c; c_s[tid] = c;
    }
    __syncthreads();
    if (tid == 0) {
        int off = 0;
        for (int e = 0; e < NEXP; e++) {
            meta[e] = off;
            cursor[e] = off;
            off += (c_s[e] + 127) & ~127;
        }
        meta[NEXP] = off;
    }
}

// K2c: slot assignment. LDS-atomic local ranks + one cursor bump/expert/block.
__global__ __launch_bounds__(256) void moe_slotfill(
    const int* __restrict__ tok_e, int* __restrict__ cursor,
    int* __restrict__ slot_token, int* __restrict__ tok_slot)
{
    __shared__ int h[NEXP];
    __shared__ int base[NEXP];
    if (threadIdx.x < NEXP) h[threadIdx.x] = 0;
    __syncthreads();
    int t = blockIdx.x * 256 + threadIdx.x;
    int e0 = tok_e[2*t],     e1 = tok_e[2*t + 1];
    int r0 = atomicAdd(&h[e0], 1);
    int r1 = atomicAdd(&h[e1], 1);
    __syncthreads();
    if (threadIdx.x < NEXP)
        base[threadIdx.x] = atomicAdd(&cursor[threadIdx.x], h[threadIdx.x]);
    __syncthreads();
    int s0 = base[e0] + r0, s1 = base[e1] + r1;
    slot_token[s0] = t;  tok_slot[2*t]     = s0;
    slot_token[s1] = t;  tok_slot[2*t + 1] = s1;
}

// ---------------------------------------------------------------------------
// K3: We [E][D][H] fp32 -> Wt [E][H][D] bf16. R7 rewrite: was 64 scalar mem
// ops/thread; now float4 loads + LDS transpose + b128 stores (~30/thread).
// Tile stride 66 ushorts: phase-1 b32 writes 2-way banked (free, m136);
// phase-2 column reads: dc-lane bank offset = 16*dc/16 mod 32 in {0,16} ->
// 2-way + same-dword broadcast (free).
// ---------------------------------------------------------------------------
__global__ __launch_bounds__(256) void moe_wtrans(
    const float* __restrict__ we, unsigned short* __restrict__ wt)
{
    __shared__ unsigned short tile[64 * 66];   // [d][h], stride 66
    int e  = blockIdx.z;
    int d0 = blockIdx.y * 64;
    int h0 = blockIdx.x * 64;
    int tid = threadIdx.x;

    // Phase 1: float4 along h. dr=tid>>4 (+16i), hc=(tid&15)*4.
    int dr = tid >> 4;
    int hc = (tid & 15) * 4;
    #pragma unroll
    for (int i = 0; i < 64; i += 16) {
        float4 v = *(const float4*)(we + ((size_t)e * DDIM + d0 + dr + i) * HDIM + h0 + hc);
        ushort2 lo; lo.x = f2b(v.x); lo.y = f2b(v.y);
        ushort2 hi; hi.x = f2b(v.z); hi.y = f2b(v.w);
        *(ushort2*)&tile[(dr + i) * 66 + hc]     = lo;   // 4B-aligned b32
        *(ushort2*)&tile[(dr + i) * 66 + hc + 2] = hi;
    }
    __syncthreads();

    // Phase 2: gather 8 consecutive d for one h, store 16B. hr=tid>>2,
    // dc=(tid&3)*16, two 8-wide chunks.
    int hr = tid >> 2;
    int dc = (tid & 3) * 16;
    #pragma unroll
    for (int sblk = 0; sblk < 2; sblk++) {
        int db = dc + sblk * 8;
        union { unsigned short u[8]; bf16x8 v; } r;
        #pragma unroll
        for (int i = 0; i < 8; i++) r.u[i] = tile[(db + i) * 66 + hr];
        *(bf16x8*)(wt + ((size_t)e * HDIM + h0 + hr) * DDIM + d0 + db) = r.v;
    }
}

// ---------------------------------------------------------------------------
// K4: grouped gather-GEMM. R7 lesson: occupancy 20->28.5% moved time 0% —
// not latency/occupancy bound. Tile traffic = 561MB/72us = 7.8 TB/s from L3
// (FETCH only 90MB): L3-BW / locality bound. Fix: XCD swizzle — 1D grid,
// n = bid%8: round-robin dispatch pins one N-column per XCD, so B working
// set per XCD = 8 experts x 256KB = 2MB -> L2-resident; A streams. K-loop
// pipeline unchanged (GLD16, A-triple/B-double, vmcnt(2) + raw s_barrier).
// ---------------------------------------------------------------------------
__global__ __launch_bounds__(256, 4) void moe_gemm(
    const unsigned short* __restrict__ xb,   // [T][D] bf16
    const unsigned short* __restrict__ wt,   // [E][H][D] bf16
    const float* __restrict__ be,            // [E][H]
    const int* __restrict__ slot_token,
    const int* __restrict__ meta,
    const int* __restrict__ counts,
    unsigned short* __restrict__ y_slot)     // [SLOT_CAP][H] bf16
{
    __shared__ __align__(16) unsigned short As[3][128 * 32];   // 24 KB
    __shared__ __align__(16) unsigned short Bs[2][128 * 32];   // 16 KB

    int bid = blockIdx.x;
    int m0 = (bid >> 3) * 128;               // bid/8: M-tile
    if (m0 >= meta[NEXP]) return;
    int n0 = (bid & 7) * 128;                // bid%8 = XCD id under round-robin

    int e = 0;
    #pragma unroll
    for (int i = 1; i < NEXP; i++) if (m0 >= meta[i]) e = i;
    int lim = meta[e] + counts[e];           // slots >= lim are padding

    int tid  = threadIdx.x;
    int lane = tid & 63, wv = tid >> 6;

    int rA = 32 * wv + (lane >> 2);
    int kc = (((lane & 3) ^ ((rA >> 1) & 3)) * 8);   // swizzled source column
    int sA0 = m0 + rA, sA1 = sA0 + 16;
    int tA0 = (sA0 < lim) ? slot_token[sA0] : 0;
    int tA1 = (sA1 < lim) ? slot_token[sA1] : 0;
    const unsigned short* gA0 = xb + (size_t)tA0 * DDIM + kc;
    const unsigned short* gA1 = xb + (size_t)tA1 * DDIM + kc;
    const unsigned short* gB0 = wt + ((size_t)e * HDIM + n0 + rA) * DDIM + kc;
    const unsigned short* gB1 = gB0 + (size_t)16 * DDIM;
    int c0 = (2 * wv) * 512;
    int c1 = c0 + 512;

    f32x4 acc[4][4];
    #pragma unroll
    for (int i = 0; i < 4; i++)
        #pragma unroll
        for (int j = 0; j < 4; j++) acc[i][j] = (f32x4){0.f, 0.f, 0.f, 0.f};

    int wm = (wv >> 1) * 64, wn = (wv & 1) * 64;
    int l16 = lane & 15, quad = lane >> 4;
    int f = (l16 >> 1) & 3;
    int rdA[4], rdB[4];
    #pragma unroll
    for (int i = 0; i < 4; i++) {
        rdA[i] = (wm + i * 16 + l16) * 32 + ((quad ^ f) * 8);
        rdB[i] = (wn + i * 16 + l16) * 32 + ((quad ^ f) * 8);
    }

#define ISSUE_A(kkv, Ab)                                                      \
    {                                                                         \
        int ko = (kkv) * 32;                                                  \
        GLD16(gA0 + ko, (Ab) + c0);                                           \
        GLD16(gA1 + ko, (Ab) + c1);                                           \
    }
#define ISSUE_B(kkv, Bb)                                                      \
    {                                                                         \
        int ko = (kkv) * 32;                                                  \
        GLD16(gB0 + ko, (Bb) + c0);                                           \
        GLD16(gB1 + ko, (Bb) + c1);                                           \
    }
#define COMPUTE(Ab, Bb)                                                       \
    {                                                                         \
        bf16x8 bfr[4];                                                        \
        _Pragma("unroll")                                                     \
        for (int j = 0; j < 4; j++)                                           \
            bfr[j] = *(const bf16x8*)((Bb) + rdB[j]);                         \
        _Pragma("unroll")                                                     \
        for (int i = 0; i < 4; i++) {                                         \
            bf16x8 af = *(const bf16x8*)((Ab) + rdA[i]);                      \
            _Pragma("unroll")                                                 \
            for (int j = 0; j < 4; j++)                                       \
                acc[i][j] = __builtin_amdgcn_mfma_f32_16x16x32_bf16(          \
                    af, bfr[j], acc[i][j], 0, 0, 0);                          \
        }                                                                     \
    }

    unsigned short *A0 = As[0], *A1 = As[1], *A2 = As[2];
    unsigned short *B0 = Bs[0], *B1 = Bs[1];

    ISSUE_A(0, A0)
    ISSUE_B(0, B0)
    ISSUE_A(1, A1)

    #pragma unroll 1
    for (int kk = 0; kk < 32; ++kk) {
        asm volatile("" ::: "memory");
        if (kk == 31) __builtin_amdgcn_s_waitcnt(0x0F70);  // vmcnt(0) tail
        else          __builtin_amdgcn_s_waitcnt(0x0F72);  // vmcnt(2)
        __builtin_amdgcn_s_barrier();
        asm volatile("" ::: "memory");
        COMPUTE(A0, B0)
        if (kk < 31) ISSUE_B(kk + 1, B1)      // B: distance-1 (L2-resident)
        if (kk < 30) ISSUE_A(kk + 2, A2)      // A: distance-2 (far gather)
        unsigned short* tA = A0; A0 = A1; A1 = A2; A2 = tA;
        unsigned short* tB = B0; B0 = B1; B1 = tB;
    }
#undef ISSUE_A
#undef ISSUE_B
#undef COMPUTE

    // Epilogue: plain bf16 stores to y_slot. C/D layout col=lane&15,
    // row=quad*4+reg (m89/m91). Pad rows skipped (never read by combine).
    #pragma unroll
    for (int i = 0; i < 4; i++) {
        #pragma unroll
        for (int r = 0; r < 4; r++) {
            int slot = m0 + wm + i * 16 + quad * 4 + r;
            if (slot >= lim) continue;
            unsigned short* yp = y_slot + (size_t)slot * HDIM + n0;
            #pragma unroll
            for (int j = 0; j < 4; j++) {
                int col = wn + j * 16 + l16;
                yp[col] = f2b(acc[i][j][r] + be[e * HDIM + n0 + col]);
            }
        }
    }
}

// ---------------------------------------------------------------------------
// K5: combine — out[t] = g0*y[s0] + g1*y[s1]. Coalesced; overwrites all out.
// ---------------------------------------------------------------------------
__global__ __launch_bounds__(256) void moe_combine(
    const unsigned short* __restrict__ y_slot,
    const int* __restrict__ tok_slot, const float* __restrict__ tok_g,
    float* __restrict__ out)
{
    int t   = blockIdx.x;
    int tid = threadIdx.x;
    int s0 = tok_slot[2 * t], s1 = tok_slot[2 * t + 1];
    float g0 = tok_g[2 * t],  g1 = tok_g[2 * t + 1];
    ushort4 a = ((const ushort4*)(y_slot + (size_t)s0 * HDIM))[tid];
    ushort4 b = ((const ushort4*)(y_slot + (size_t)s1 * HDIM))[tid];
    float4 o;
    o.x = g0 * b2f(a.x) + g1 * b2f(b.x);
    o.y = g0 * b2f(a.y) + g1 * b2f(b.y);
    o.z = g0 * b2f(a.z) + g1 * b2f(b.z);
    o.w = g0 * b2f(a.w) + g1 * b2f(b.w);
    ((float4*)(out + (size_t)t * HDIM))[tid] = o;
}

extern "C" void kernel_launch(void* const* d_in, const int* in_sizes, int n_in,
                              void* d_out, int out_size, void* d_ws, size_t ws_size,
                              hipStream_t stream) {
    const float* x  = (const float*)d_in[0];   // [B,S,D] fp32
    const float* wg = (const float*)d_in[1];   // [D,E]
    const float* we = (const float*)d_in[2];   // [E,D,H]
    const float* be = (const float*)d_in[3];   // [E,H]
    float* out = (float*)d_out;

    char* ws = (char*)d_ws;
    size_t o = 0;
    auto alloc = [&](size_t bytes) -> void* {
        void* p = ws + o;
        o = (o + bytes + 255) & ~(size_t)255;
        return p;
    };
    unsigned short* xb   = (unsigned short*)alloc((size_t)T_TOK * DDIM * 2);
    unsigned short* wtb  = (unsigned short*)alloc((size_t)NEXP * HDIM * DDIM * 2);
    unsigned short* ysl  = (unsigned short*)alloc((size_t)SLOT_CAP * HDIM * 2);
    int*   slot_token    = (int*)  alloc((size_t)SLOT_CAP * 4);
    int*   cnt_part      = (int*)  alloc((size_t)NCBLK * NEXP * 4);
    int*   counts        = (int*)  alloc(NEXP * 4);
    int*   meta          = (int*)  alloc((NEXP + 1) * 4);
    int*   cursor        = (int*)  alloc(NEXP * 4);
    int*   tok_e         = (int*)  alloc((size_t)T_TOK * 2 * 4);
    float* tok_g         = (float*)alloc((size_t)T_TOK * 2 * 4);
    int*   tok_slot      = (int*)  alloc((size_t)T_TOK * 2 * 4);

    // 7 graph nodes, no memsets.
    moe_routing<<<T_TOK, 256, 0, stream>>>(x, wg, xb, tok_e, tok_g);
    moe_count<<<NCBLK, 256, 0, stream>>>(tok_e, cnt_part);
    moe_offsets<<<1, 64, 0, stream>>>(cnt_part, meta, counts, cursor);
    moe_slotfill<<<NCBLK, 256, 0, stream>>>(tok_e, cursor, slot_token, tok_slot);
    moe_wtrans<<<dim3(HDIM / 64, DDIM / 64, NEXP), 256, 0, stream>>>(we, wtb);
    moe_gemm<<<8 * (SLOT_CAP / 128), 256, 0, stream>>>(
        xb, wtb, be, slot_token, meta, counts, ysl);
    moe_combine<<<T_TOK, 256, 0, stream>>>(ysl, tok_slot, tok_g, out);
}